// Round 2
// baseline (2294.084 us; speedup 1.0000x reference)
//
#include <hip/hip_runtime.h>

#define HW 784
#define WD 28

// ---------------------------------------------------------------------------
// Prep: fold BN into transposed weight layouts.
// ---------------------------------------------------------------------------
__global__ void k_prep(
    const float* __restrict__ w_down, const float* __restrict__ b_down,
    const float* __restrict__ bn1_g, const float* __restrict__ bn1_b,
    const float* __restrict__ bn1_m, const float* __restrict__ bn1_v,
    const float* __restrict__ tconv_w, const float* __restrict__ tconv_b,
    const float* __restrict__ bnt_g, const float* __restrict__ bnt_b,
    const float* __restrict__ bnt_m, const float* __restrict__ bnt_v,
    const float* __restrict__ off3_w, const float* __restrict__ def3_w,
    const float* __restrict__ off5_w, const float* __restrict__ def5_w,
    const float* __restrict__ conv1_w, const float* __restrict__ conv1_b,
    const float* __restrict__ bn3_g, const float* __restrict__ bn3_b,
    const float* __restrict__ bn3_m, const float* __restrict__ bn3_v,
    const float* __restrict__ conv_w, const float* __restrict__ conv_b,
    const float* __restrict__ bn2_g, const float* __restrict__ bn2_b,
    const float* __restrict__ bn2_m, const float* __restrict__ bn2_v,
    float* __restrict__ wdownT, float* __restrict__ bias1,
    float* __restrict__ wtT, float* __restrict__ AtBt,
    float* __restrict__ off3T, float* __restrict__ off5T,
    float* __restrict__ def3T, float* __restrict__ def5T,
    float* __restrict__ c1T, float* __restrict__ B3,
    float* __restrict__ gwT, float* __restrict__ Bg)
{
  const int tid = blockIdx.x * blockDim.x + threadIdx.x;
  const int nth = gridDim.x * blockDim.x;
  for (int i = tid; i < 256 * 64; i += nth) {
    int c = i >> 6, cr = i & 63;
    float s = bn1_g[cr] / sqrtf(bn1_v[cr] + 1e-5f);
    wdownT[i] = w_down[cr * 256 + c] * s;
  }
  for (int i = tid; i < 64; i += nth) {
    float s = bn1_g[i] / sqrtf(bn1_v[i] + 1e-5f);
    bias1[i] = (b_down[i] - bn1_m[i]) * s + bn1_b[i];
  }
  for (int i = tid; i < 192 * 9 * 64; i += nth) {
    int cc = i / (9 * 64); int tap = (i / 64) % 9; int o = i & 63;
    int dt = cc >> 6, c = cc & 63;
    wtT[i] = tconv_w[o * 1728 + c * 27 + dt * 9 + tap];
  }
  for (int i = tid; i < 64; i += nth) {
    float s = bnt_g[i] / sqrtf(bnt_v[i] + 1e-5f);
    AtBt[i] = s * 0.125f;
    AtBt[64 + i] = (tconv_b[i] - bnt_m[i]) * s + bnt_b[i];
  }
  for (int i = tid; i < 64 * 9 * 18; i += nth) {
    int c = i / (9 * 18); int tap = (i / 18) % 9; int oc = i % 18;
    off3T[i] = off3_w[oc * 576 + c * 9 + tap];
  }
  for (int i = tid; i < 64 * 25 * 50; i += nth) {
    int c = i / 1250; int tap = (i / 50) % 25; int oc = i % 50;
    off5T[i] = off5_w[oc * 1600 + c * 25 + tap];
  }
  for (int i = tid; i < 9 * 64 * 64; i += nth) {
    int k = i >> 12; int c = (i >> 6) & 63; int o = i & 63;
    def3T[i] = def3_w[o * 576 + c * 9 + k];
  }
  for (int i = tid; i < 25 * 64 * 64; i += nth) {
    int k = i >> 12; int c = (i >> 6) & 63; int o = i & 63;
    def5T[i] = def5_w[o * 1600 + c * 25 + k];
  }
  for (int i = tid; i < 64 * 64; i += nth) {
    int c = i >> 6, o = i & 63;
    float s = bn3_g[o] / sqrtf(bn3_v[o] + 1e-5f);
    c1T[i] = conv1_w[o * 64 + c] * s;
  }
  for (int i = tid; i < 64; i += nth) {
    float s = bn3_g[i] / sqrtf(bn3_v[i] + 1e-5f);
    B3[i] = (conv1_b[i] - bn3_m[i]) * s + bn3_b[i];
  }
  for (int i = tid; i < 64 * 256; i += nth) {
    int c = i >> 8, co = i & 255;
    float s = bn2_g[co] / sqrtf(bn2_v[co] + 1e-5f);
    gwT[i] = conv_w[co * 64 + c] * s;
  }
  for (int i = tid; i < 256; i += nth) {
    float s = bn2_g[i] / sqrtf(bn2_v[i] + 1e-5f);
    Bg[i] = (conv_b[i] - bn2_m[i]) * s + bn2_b[i];
  }
}

// ---------------------------------------------------------------------------
// 1x1 down conv (256->64) + BN fold. o-split x2 via blockIdx.z (occupancy).
// ---------------------------------------------------------------------------
__global__ __launch_bounds__(256) void k_down(
    const float* __restrict__ x, const float* __restrict__ wdownT,
    const float* __restrict__ bias1, float* __restrict__ out)
{
  __shared__ float wl[256 * 32];            // 32 KB
  const int tid = threadIdx.x;
  const int o0 = blockIdx.z * 32;
  for (int i = tid; i < 2048; i += 256) {   // 256c x 8 quads
    int c = i >> 3, q = i & 7;
    ((float4*)wl)[i] = *(const float4*)(wdownT + c * 64 + o0 + q * 4);
  }
  __syncthreads();
  const int f = blockIdx.x;
  const int px = blockIdx.y * 256 + tid;
  const bool act = px < HW;
  const int pxe = act ? px : 0;
  const float* xp = x + (size_t)f * 256 * HW + pxe;
  float acc[32];
#pragma unroll
  for (int j = 0; j < 32; j++) acc[j] = 0.f;
#pragma unroll 4
  for (int c = 0; c < 256; c++) {
    float xv = xp[c * HW];
    const float* wr = &wl[c * 32];
#pragma unroll
    for (int j = 0; j < 32; j++) acc[j] += xv * wr[j];
  }
  if (act) {
    float* op = out + (size_t)f * 64 * HW + px;
#pragma unroll
    for (int j = 0; j < 32; j++) op[(o0 + j) * HW] = acc[j] + bias1[o0 + j];
  }
}

// ---------------------------------------------------------------------------
// U planes for collapsed temporal conv.
// ---------------------------------------------------------------------------
__global__ void k_makeU(const float* __restrict__ out, float* __restrict__ U)
{
  const int idx = blockIdx.x * 256 + threadIdx.x;
  const int b = idx / (64 * HW);
  const int r = idx % (64 * HW);
  const float* p = out + (size_t)b * 8 * 64 * HW + r;
  float v0 = p[0];
  float s = v0, v = v0;
#pragma unroll
  for (int t = 1; t < 8; t++) { v = p[t * 64 * HW]; s += v; }
  float* u = U + (size_t)b * 192 * HW + r;
  u[0] = s - v;
  u[64 * HW] = s;
  u[128 * HW] = s - v0;
}

// ---------------------------------------------------------------------------
// Collapsed temporal conv: 3x3, 192->64. o-groups of 4 (16 z-blocks).
// ---------------------------------------------------------------------------
__global__ __launch_bounds__(256) void k_tconv(
    const float* __restrict__ U, const float* __restrict__ wtT,
    const float* __restrict__ AtBt, float* __restrict__ t_out)
{
  __shared__ float wl[16 * 9 * 4];
  const int tid = threadIdx.x;
  const int b = blockIdx.x;
  const int px = blockIdx.y * 256 + tid;
  const int o0 = blockIdx.z * 4;
  const bool act = px < HW;
  const int pxe = act ? px : 0;
  const int y = pxe / WD, x = pxe % WD;
  int lin[9]; float msk[9];
#pragma unroll
  for (int t = 0; t < 9; t++) {
    int iy = y + t / 3 - 1, ix = x + t % 3 - 1;
    bool ok = iy >= 0 && iy < WD && ix >= 0 && ix < WD;
    lin[t] = min(max(iy, 0), WD - 1) * WD + min(max(ix, 0), WD - 1);
    msk[t] = ok ? 1.f : 0.f;
  }
  float acc[4];
#pragma unroll
  for (int j = 0; j < 4; j++) acc[j] = 0.f;
  const float* ub = U + (size_t)b * 192 * HW;
  for (int ccb = 0; ccb < 12; ccb++) {
    __syncthreads();
    for (int i = tid; i < 576; i += 256) {
      int ccL = i / 36; int rr = i % 36; int tap = rr >> 2; int j = rr & 3;
      wl[i] = wtT[((ccb * 16 + ccL) * 9 + tap) * 64 + o0 + j];
    }
    __syncthreads();
    for (int ccL = 0; ccL < 16; ccL++) {
      const float* p = ub + (ccb * 16 + ccL) * HW;
      float v[9];
#pragma unroll
      for (int t = 0; t < 9; t++) v[t] = p[lin[t]] * msk[t];
      const float* wr = &wl[ccL * 36];
#pragma unroll
      for (int t = 0; t < 9; t++)
#pragma unroll
        for (int j = 0; j < 4; j++) acc[j] += v[t] * wr[t * 4 + j];
    }
  }
  if (act) {
#pragma unroll
    for (int j = 0; j < 4; j++) {
      int o = o0 + j;
      t_out[(size_t)(b * 64 + o) * HW + px] = acc[j] * AtBt[o] + AtBt[64 + o];
    }
  }
}

// ---------------------------------------------------------------------------
// Offset convs: KSxKS conv 64->OC; oc-split OSUB per block via blockIdx.z.
// ---------------------------------------------------------------------------
template <int KS, int PAD, int OC, int CCH, int OSUB>
__global__ __launch_bounds__(256) void k_offconv(
    const float* __restrict__ frames, const float* __restrict__ wT,
    const float* __restrict__ bias, float* __restrict__ dst)
{
  constexpr int K2 = KS * KS;
  __shared__ float wl[CCH * K2 * OSUB];
  const int tid = threadIdx.x;
  const int n = blockIdx.x;
  const int f = (n / 7) * 8 + (n % 7) + 1;
  const int px = blockIdx.y * 256 + tid;
  const int oc0 = blockIdx.z * OSUB;
  const bool act = px < HW;
  const int pxe = act ? px : 0;
  const int y = pxe / WD, x = pxe % WD;
  int lin[K2]; float msk[K2];
#pragma unroll
  for (int t = 0; t < K2; t++) {
    int iy = y + t / KS - PAD, ix = x + t % KS - PAD;
    bool ok = iy >= 0 && iy < WD && ix >= 0 && ix < WD;
    lin[t] = min(max(iy, 0), WD - 1) * WD + min(max(ix, 0), WD - 1);
    msk[t] = ok ? 1.f : 0.f;
  }
  float acc[OSUB];
#pragma unroll
  for (int j = 0; j < OSUB; j++) acc[j] = 0.f;
  const float* sb = frames + (size_t)f * 64 * HW;
  for (int cb = 0; cb < 64 / CCH; cb++) {
    __syncthreads();
    for (int i = tid; i < CCH * K2 * OSUB; i += 256) {
      int c = i / (K2 * OSUB); int tap = (i / OSUB) % K2; int j = i % OSUB;
      wl[i] = wT[((cb * CCH + c) * K2 + tap) * OC + oc0 + j];
    }
    __syncthreads();
    for (int cL = 0; cL < CCH; cL++) {
      const float* p = sb + (cb * CCH + cL) * HW;
      float v[K2];
#pragma unroll
      for (int t = 0; t < K2; t++) v[t] = p[lin[t]] * msk[t];
      const float* wr = &wl[cL * K2 * OSUB];
#pragma unroll
      for (int t = 0; t < K2; t++)
#pragma unroll
        for (int j = 0; j < OSUB; j++) acc[j] += v[t] * wr[t * OSUB + j];
    }
  }
  if (act) {
#pragma unroll
    for (int j = 0; j < OSUB; j++)
      dst[(size_t)(n * OC + oc0 + j) * HW + px] = acc[j] + bias[oc0 + j];
  }
}

// ---------------------------------------------------------------------------
// Deformable conv; o-split x4 (16 o-channels per block) via blockIdx.z.
// Bilinear gather per (k,c) with validity folded into corner weights.
// ---------------------------------------------------------------------------
template <int KS, int PAD, bool ACCUM>
__global__ __launch_bounds__(256) void k_deform(
    const float* __restrict__ frames, const float* __restrict__ offs,
    const float* __restrict__ wT, float* __restrict__ dst)
{
  constexpr int K2 = KS * KS;
  __shared__ float wl[64 * 16];             // 4 KB
  const int tid = threadIdx.x;
  const int n = blockIdx.x;
  const int f = (n / 7) * 8 + (n % 7) + 1;
  const int px = blockIdx.y * 256 + tid;
  const int o0 = blockIdx.z * 16;
  const bool act = px < HW;
  const int pxe = act ? px : 0;
  const int y = pxe / WD, x = pxe % WD;
  const float* sb = frames + (size_t)f * 64 * HW;
  const float* ob = offs + (size_t)n * (2 * K2) * HW + pxe;
  float acc[16];
#pragma unroll
  for (int j = 0; j < 16; j++) acc[j] = 0.f;
  for (int k = 0; k < K2; k++) {
    __syncthreads();
    {
      int c = tid >> 2, q = tid & 3;        // 256 threads = 64c x 4 quads
      ((float4*)wl)[tid] = *(const float4*)(wT + k * 4096 + c * 64 + o0 + q * 4);
    }
    __syncthreads();
    float offy = ob[(2 * k) * HW];
    float offx = ob[(2 * k + 1) * HW];
    float py = (float)(y + k / KS - PAD) + offy;
    float pxx = (float)(x + k % KS - PAD) + offx;
    float fy = floorf(py), fx = floorf(pxx);
    int y0 = (int)fy, x0 = (int)fx;
    float ly = py - fy, lx = pxx - fx;
    int y1 = y0 + 1, x1 = x0 + 1;
    float vy0 = (y0 >= 0 && y0 < WD) ? 1.f : 0.f;
    float vy1 = (y1 >= 0 && y1 < WD) ? 1.f : 0.f;
    float vx0 = (x0 >= 0 && x0 < WD) ? 1.f : 0.f;
    float vx1 = (x1 >= 0 && x1 < WD) ? 1.f : 0.f;
    float w00 = (1.f - ly) * (1.f - lx) * vy0 * vx0;
    float w01 = (1.f - ly) * lx * vy0 * vx1;
    float w10 = ly * (1.f - lx) * vy1 * vx0;
    float w11 = ly * lx * vy1 * vx1;
    int cy0 = min(max(y0, 0), WD - 1), cy1 = min(max(y1, 0), WD - 1);
    int cx0 = min(max(x0, 0), WD - 1), cx1 = min(max(x1, 0), WD - 1);
    int l00 = cy0 * WD + cx0, l01 = cy0 * WD + cx1;
    int l10 = cy1 * WD + cx0, l11 = cy1 * WD + cx1;
    float n00 = sb[l00], n01 = sb[l01], n10 = sb[l10], n11 = sb[l11];
    for (int c = 0; c < 64; c++) {
      float g00 = n00, g01 = n01, g10 = n10, g11 = n11;
      if (c < 63) {
        const float* q = sb + (c + 1) * HW;
        n00 = q[l00]; n01 = q[l01]; n10 = q[l10]; n11 = q[l11];
      }
      float g = g00 * w00 + g01 * w01 + g10 * w10 + g11 * w11;
      const float* wr = &wl[c * 16];
#pragma unroll
      for (int j = 0; j < 16; j++) acc[j] += g * wr[j];
    }
  }
  if (act) {
    float* dp = dst + (size_t)n * 64 * HW + px;
#pragma unroll
    for (int j = 0; j < 16; j++) {
      if (ACCUM) dp[(o0 + j) * HW] += acc[j];
      else dp[(o0 + j) * HW] = acc[j];
    }
  }
}

// ---------------------------------------------------------------------------
// maxpool 3x3 + 1x1 conv (BN folded) + diff epilogue; o-split x2.
// ---------------------------------------------------------------------------
__global__ __launch_bounds__(256) void k_davg_diff(
    const float* __restrict__ frames, const float* __restrict__ c1T,
    const float* __restrict__ B3, float* __restrict__ dsum)
{
  __shared__ float wl[64 * 32];
  const int tid = threadIdx.x;
  const int o0 = blockIdx.z * 32;
  for (int i = tid; i < 512; i += 256) {    // 64c x 8 quads
    int c = i >> 3, q = i & 7;
    ((float4*)wl)[i] = *(const float4*)(c1T + c * 64 + o0 + q * 4);
  }
  __syncthreads();
  const int n = blockIdx.x;
  const int b = n / 7, t = n % 7;
  const int fpost = b * 8 + t + 1, fpre = b * 8 + t;
  const int px = blockIdx.y * 256 + tid;
  const bool act = px < HW;
  const int pxe = act ? px : 0;
  const int y = pxe / WD, x = pxe % WD;
  int lin[9]; bool okm[9];
#pragma unroll
  for (int t2 = 0; t2 < 9; t2++) {
    int iy = y + t2 / 3 - 1, ix = x + t2 % 3 - 1;
    okm[t2] = iy >= 0 && iy < WD && ix >= 0 && ix < WD;
    lin[t2] = min(max(iy, 0), WD - 1) * WD + min(max(ix, 0), WD - 1);
  }
  float acc[32];
#pragma unroll
  for (int j = 0; j < 32; j++) acc[j] = 0.f;
  const float* sb = frames + (size_t)fpost * 64 * HW;
  for (int c = 0; c < 64; c++) {
    const float* p = sb + c * HW;
    float m = -1e30f;
#pragma unroll
    for (int t2 = 0; t2 < 9; t2++) {
      float v = okm[t2] ? p[lin[t2]] : -1e30f;
      m = fmaxf(m, v);
    }
    const float* wr = &wl[c * 32];
#pragma unroll
    for (int j = 0; j < 32; j++) acc[j] += m * wr[j];
  }
  if (act) {
    const float* xpre = frames + (size_t)fpre * 64 * HW + px;
    float* dp = dsum + (size_t)n * 64 * HW + px;
#pragma unroll
    for (int j = 0; j < 32; j++) {
      int o = o0 + j;
      float d = dp[o * HW] + (acc[j] + B3[o]) - 3.f * xpre[o * HW];
      dp[o * HW] = fabsf(d);
    }
  }
}

// ---------------------------------------------------------------------------
// Spatial mean of cat = [diff frames | t_out] per (nt, c).
// ---------------------------------------------------------------------------
__global__ void k_gmean(const float* __restrict__ dsum,
                        const float* __restrict__ t_out,
                        float* __restrict__ gmean)
{
  const int nt = blockIdx.x, c = blockIdx.y;
  const int b = nt >> 3, tt = nt & 7;
  const float* p = (tt < 7) ? (dsum + (size_t)((b * 7 + tt) * 64 + c) * HW)
                            : (t_out + (size_t)(b * 64 + c) * HW);
  const int tid = threadIdx.x;
  float s = 0.f;
  for (int i = tid; i < HW; i += 64) s += p[i];
#pragma unroll
  for (int o = 32; o > 0; o >>= 1) s += __shfl_down(s, o, 64);
  if (tid == 0) gmean[nt * 64 + c] = s * (1.f / HW);
}

// ---------------------------------------------------------------------------
// Gate: 1x1 conv 64->256 + sigmoid; store mult = 1+gate-0.5 form.
// ---------------------------------------------------------------------------
__global__ __launch_bounds__(256) void k_gate(
    const float* __restrict__ gmean, const float* __restrict__ gwT,
    const float* __restrict__ Bg, float* __restrict__ mult)
{
  __shared__ float gm[64];
  const int nt = blockIdx.x, co = threadIdx.x;
  if (co < 64) gm[co] = gmean[nt * 64 + co];
  __syncthreads();
  float a = 0.f;
#pragma unroll 8
  for (int c = 0; c < 64; c++) a += gm[c] * gwT[c * 256 + co];
  float pre = a + Bg[co];
  mult[nt * 256 + co] = 0.5f + 1.f / (1.f + expf(-pre));
}

// ---------------------------------------------------------------------------
// out = x * mult[nt,co]
// ---------------------------------------------------------------------------
__global__ void k_apply(const float* __restrict__ x,
                        const float* __restrict__ mult,
                        float* __restrict__ outp)
{
  const int i = blockIdx.x * 256 + threadIdx.x;
  const int plane = i / 196;
  const float m = mult[plane];
  float4 v = ((const float4*)x)[i];
  v.x *= m; v.y *= m; v.z *= m; v.w *= m;
  ((float4*)outp)[i] = v;
}

// ---------------------------------------------------------------------------
extern "C" void kernel_launch(void* const* d_in, const int* in_sizes, int n_in,
                              void* d_out, int out_size, void* d_ws, size_t ws_size,
                              hipStream_t stream)
{
  const float* x       = (const float*)d_in[0];
  const float* w_down  = (const float*)d_in[1];
  const float* b_down  = (const float*)d_in[2];
  const float* bn1_g   = (const float*)d_in[3];
  const float* bn1_b   = (const float*)d_in[4];
  const float* bn1_m   = (const float*)d_in[5];
  const float* bn1_v   = (const float*)d_in[6];
  const float* tconv_w = (const float*)d_in[7];
  const float* tconv_b = (const float*)d_in[8];
  const float* bnt_g   = (const float*)d_in[9];
  const float* bnt_b   = (const float*)d_in[10];
  const float* bnt_m   = (const float*)d_in[11];
  const float* bnt_v   = (const float*)d_in[12];
  const float* off3_w  = (const float*)d_in[13];
  const float* off3_b  = (const float*)d_in[14];
  const float* def3_w  = (const float*)d_in[15];
  const float* off5_w  = (const float*)d_in[16];
  const float* off5_b  = (const float*)d_in[17];
  const float* def5_w  = (const float*)d_in[18];
  const float* conv1_w = (const float*)d_in[19];
  const float* conv1_b = (const float*)d_in[20];
  const float* bn3_g   = (const float*)d_in[21];
  const float* bn3_b   = (const float*)d_in[22];
  const float* bn3_m   = (const float*)d_in[23];
  const float* bn3_v   = (const float*)d_in[24];
  const float* conv_w  = (const float*)d_in[25];
  const float* conv_b  = (const float*)d_in[26];
  const float* bn2_g   = (const float*)d_in[27];
  const float* bn2_b   = (const float*)d_in[28];
  const float* bn2_m   = (const float*)d_in[29];
  const float* bn2_v   = (const float*)d_in[30];

  float* ws = (float*)d_ws;
  float* out_b  = ws; ws += 64 * 64 * HW;
  float* U      = ws; ws += 8 * 192 * HW;
  float* t_out  = ws; ws += 8 * 64 * HW;
  float* off3b  = ws; ws += 56 * 18 * HW;
  float* off5b  = ws; ws += 56 * 50 * HW;
  float* dsum   = ws; ws += 56 * 64 * HW;
  float* gmean  = ws; ws += 64 * 64;
  float* multb  = ws; ws += 64 * 256;
  float* wdownT = ws; ws += 256 * 64;
  float* bias1  = ws; ws += 64;
  float* wtT    = ws; ws += 192 * 9 * 64;
  float* AtBt   = ws; ws += 128;
  float* off3T  = ws; ws += 64 * 9 * 18;
  float* off5T  = ws; ws += 64 * 25 * 50;
  float* def3T  = ws; ws += 9 * 64 * 64;
  float* def5T  = ws; ws += 25 * 64 * 64;
  float* c1T    = ws; ws += 64 * 64;
  float* B3     = ws; ws += 64;
  float* gwT    = ws; ws += 64 * 256;
  float* Bg     = ws; ws += 256;

  k_prep<<<256, 256, 0, stream>>>(
      w_down, b_down, bn1_g, bn1_b, bn1_m, bn1_v,
      tconv_w, tconv_b, bnt_g, bnt_b, bnt_m, bnt_v,
      off3_w, def3_w, off5_w, def5_w,
      conv1_w, conv1_b, bn3_g, bn3_b, bn3_m, bn3_v,
      conv_w, conv_b, bn2_g, bn2_b, bn2_m, bn2_v,
      wdownT, bias1, wtT, AtBt, off3T, off5T, def3T, def5T,
      c1T, B3, gwT, Bg);

  k_down<<<dim3(64, 4, 2), 256, 0, stream>>>(x, wdownT, bias1, out_b);
  k_makeU<<<1568, 256, 0, stream>>>(out_b, U);
  k_tconv<<<dim3(8, 4, 16), 256, 0, stream>>>(U, wtT, AtBt, t_out);
  k_offconv<3, 1, 18, 16, 6><<<dim3(56, 4, 3), 256, 0, stream>>>(out_b, off3T, off3_b, off3b);
  k_offconv<5, 2, 50, 8, 10><<<dim3(56, 4, 5), 256, 0, stream>>>(out_b, off5T, off5_b, off5b);
  k_deform<3, 1, false><<<dim3(56, 4, 4), 256, 0, stream>>>(out_b, off3b, def3T, dsum);
  k_deform<5, 2, true><<<dim3(56, 4, 4), 256, 0, stream>>>(out_b, off5b, def5T, dsum);
  k_davg_diff<<<dim3(56, 4, 2), 256, 0, stream>>>(out_b, c1T, B3, dsum);
  k_gmean<<<dim3(64, 64), 64, 0, stream>>>(dsum, t_out, gmean);
  k_gate<<<64, 256, 0, stream>>>(gmean, gwT, Bg, multb);
  k_apply<<<12544, 256, 0, stream>>>(x, multb, (float*)d_out);
}

// Round 4
// 1016.646 us; speedup vs baseline: 2.2565x; 2.2565x over previous
//
#include <hip/hip_runtime.h>

#define HW 784
#define WD 28
#define NPX (56 * HW)          // 43904 deform/offconv pixels
#define PXBLK 172              // ceil(43904/256)
#define PLANE (56 * 64 * HW)   // 2,809,856 floats: one partial plane

// ---------------------------------------------------------------------------
// Prep: fold BN into transposed weight layouts.
// ---------------------------------------------------------------------------
__global__ void k_prep(
    const float* __restrict__ w_down, const float* __restrict__ b_down,
    const float* __restrict__ bn1_g, const float* __restrict__ bn1_b,
    const float* __restrict__ bn1_m, const float* __restrict__ bn1_v,
    const float* __restrict__ tconv_w, const float* __restrict__ tconv_b,
    const float* __restrict__ bnt_g, const float* __restrict__ bnt_b,
    const float* __restrict__ bnt_m, const float* __restrict__ bnt_v,
    const float* __restrict__ off3_w, const float* __restrict__ def3_w,
    const float* __restrict__ off5_w, const float* __restrict__ def5_w,
    const float* __restrict__ conv1_w, const float* __restrict__ conv1_b,
    const float* __restrict__ bn3_g, const float* __restrict__ bn3_b,
    const float* __restrict__ bn3_m, const float* __restrict__ bn3_v,
    const float* __restrict__ conv_w, const float* __restrict__ conv_b,
    const float* __restrict__ bn2_g, const float* __restrict__ bn2_b,
    const float* __restrict__ bn2_m, const float* __restrict__ bn2_v,
    float* __restrict__ wdownT, float* __restrict__ bias1,
    float* __restrict__ wtT, float* __restrict__ AtBt,
    float* __restrict__ off3T, float* __restrict__ off5T,
    float* __restrict__ def3T, float* __restrict__ def5T,
    float* __restrict__ c1T, float* __restrict__ B3,
    float* __restrict__ gwT, float* __restrict__ Bg)
{
  const int tid = blockIdx.x * blockDim.x + threadIdx.x;
  const int nth = gridDim.x * blockDim.x;
  for (int i = tid; i < 256 * 64; i += nth) {
    int c = i >> 6, cr = i & 63;
    float s = bn1_g[cr] / sqrtf(bn1_v[cr] + 1e-5f);
    wdownT[i] = w_down[cr * 256 + c] * s;
  }
  for (int i = tid; i < 64; i += nth) {
    float s = bn1_g[i] / sqrtf(bn1_v[i] + 1e-5f);
    bias1[i] = (b_down[i] - bn1_m[i]) * s + bn1_b[i];
  }
  for (int i = tid; i < 192 * 9 * 64; i += nth) {
    int cc = i / (9 * 64); int tap = (i / 64) % 9; int o = i & 63;
    int dt = cc >> 6, c = cc & 63;
    wtT[i] = tconv_w[o * 1728 + c * 27 + dt * 9 + tap];
  }
  for (int i = tid; i < 64; i += nth) {
    float s = bnt_g[i] / sqrtf(bnt_v[i] + 1e-5f);
    AtBt[i] = s * 0.125f;
    AtBt[64 + i] = (tconv_b[i] - bnt_m[i]) * s + bnt_b[i];
  }
  for (int i = tid; i < 64 * 9 * 18; i += nth) {
    int c = i / (9 * 18); int tap = (i / 18) % 9; int oc = i % 18;
    off3T[i] = off3_w[oc * 576 + c * 9 + tap];
  }
  for (int i = tid; i < 64 * 25 * 50; i += nth) {
    int c = i / 1250; int tap = (i / 50) % 25; int oc = i % 50;
    off5T[i] = off5_w[oc * 1600 + c * 25 + tap];
  }
  for (int i = tid; i < 9 * 64 * 64; i += nth) {
    int k = i >> 12; int c = (i >> 6) & 63; int o = i & 63;
    def3T[i] = def3_w[o * 576 + c * 9 + k];
  }
  for (int i = tid; i < 25 * 64 * 64; i += nth) {
    int k = i >> 12; int c = (i >> 6) & 63; int o = i & 63;
    def5T[i] = def5_w[o * 1600 + c * 25 + k];
  }
  for (int i = tid; i < 64 * 64; i += nth) {
    int c = i >> 6, o = i & 63;
    float s = bn3_g[o] / sqrtf(bn3_v[o] + 1e-5f);
    c1T[i] = conv1_w[o * 64 + c] * s;
  }
  for (int i = tid; i < 64; i += nth) {
    float s = bn3_g[i] / sqrtf(bn3_v[i] + 1e-5f);
    B3[i] = (conv1_b[i] - bn3_m[i]) * s + bn3_b[i];
  }
  for (int i = tid; i < 64 * 256; i += nth) {
    int c = i >> 8, co = i & 255;
    float s = bn2_g[co] / sqrtf(bn2_v[co] + 1e-5f);
    gwT[i] = conv_w[co * 64 + c] * s;
  }
  for (int i = tid; i < 256; i += nth) {
    float s = bn2_g[i] / sqrtf(bn2_v[i] + 1e-5f);
    Bg[i] = (conv_b[i] - bn2_m[i]) * s + bn2_b[i];
  }
}

// ---------------------------------------------------------------------------
// 1x1 down conv (256->64) + BN fold. px-flat grid (196, o-split 2).
// ---------------------------------------------------------------------------
__global__ __launch_bounds__(256) void k_down(
    const float* __restrict__ x, const float* __restrict__ wdownT,
    const float* __restrict__ bias1, float* __restrict__ out)
{
  __shared__ float wl[256 * 32];            // 32 KB
  const int tid = threadIdx.x;
  const int o0 = blockIdx.y * 32;
  for (int i = tid; i < 2048; i += 256) {
    int c = i >> 3, q = i & 7;
    ((float4*)wl)[i] = *(const float4*)(wdownT + c * 64 + o0 + q * 4);
  }
  __syncthreads();
  const int gpx = blockIdx.x * 256 + tid;   // < 50176 exact
  const int f = gpx / HW, px = gpx % HW;
  const float* xp = x + (size_t)f * 256 * HW + px;
  float acc[32];
#pragma unroll
  for (int j = 0; j < 32; j++) acc[j] = 0.f;
#pragma unroll 4
  for (int c = 0; c < 256; c++) {
    float xv = xp[c * HW];
    const float* wr = &wl[c * 32];
#pragma unroll
    for (int j = 0; j < 32; j++) acc[j] += xv * wr[j];
  }
  float* op = out + (size_t)f * 64 * HW + px;
#pragma unroll
  for (int j = 0; j < 32; j++) op[(o0 + j) * HW] = acc[j] + bias1[o0 + j];
}

// ---------------------------------------------------------------------------
// Transpose post frames to px-major: xT[n][px][c], n over 56 post frames.
// ---------------------------------------------------------------------------
__global__ __launch_bounds__(256) void k_xpose(
    const float* __restrict__ out_b, float* __restrict__ xT)
{
  __shared__ float t[64 * 65];
  const int tid = threadIdx.x;
  const int lane = tid & 63, grp = tid >> 6;
  const int n = blockIdx.x;
  const int f = (n / 7) * 8 + (n % 7) + 1;
  const int px0 = blockIdx.y * 64;
  const float* sb = out_b + (size_t)f * 64 * HW;
#pragma unroll
  for (int c = grp; c < 64; c += 4) {
    int px = px0 + lane;
    t[c * 65 + lane] = (px < HW) ? sb[c * HW + px] : 0.f;
  }
  __syncthreads();
#pragma unroll
  for (int r = grp; r < 64; r += 4) {
    int px = px0 + r;
    if (px < HW) xT[((size_t)n * HW + px) * 64 + lane] = t[lane * 65 + r];
  }
}

// ---------------------------------------------------------------------------
// U planes for collapsed temporal conv.
// ---------------------------------------------------------------------------
__global__ void k_makeU(const float* __restrict__ out, float* __restrict__ U)
{
  const int idx = blockIdx.x * 256 + threadIdx.x;
  const int b = idx / (64 * HW);
  const int r = idx % (64 * HW);
  const float* p = out + (size_t)b * 8 * 64 * HW + r;
  float v0 = p[0];
  float s = v0, v = v0;
#pragma unroll
  for (int t = 1; t < 8; t++) { v = p[t * 64 * HW]; s += v; }
  float* u = U + (size_t)b * 192 * HW + r;
  u[0] = s - v;
  u[64 * HW] = s;
  u[128 * HW] = s - v0;
}

// ---------------------------------------------------------------------------
// Collapsed temporal conv: 3x3, 192->64. o-groups of 4 (16 z-blocks).
// ---------------------------------------------------------------------------
__global__ __launch_bounds__(256) void k_tconv(
    const float* __restrict__ U, const float* __restrict__ wtT,
    const float* __restrict__ AtBt, float* __restrict__ t_out)
{
  __shared__ float wl[16 * 9 * 4];
  const int tid = threadIdx.x;
  const int b = blockIdx.x;
  const int px = blockIdx.y * 256 + tid;
  const int o0 = blockIdx.z * 4;
  const bool act = px < HW;
  const int pxe = act ? px : 0;
  const int y = pxe / WD, x = pxe % WD;
  int lin[9]; float msk[9];
#pragma unroll
  for (int t = 0; t < 9; t++) {
    int iy = y + t / 3 - 1, ix = x + t % 3 - 1;
    bool ok = iy >= 0 && iy < WD && ix >= 0 && ix < WD;
    lin[t] = min(max(iy, 0), WD - 1) * WD + min(max(ix, 0), WD - 1);
    msk[t] = ok ? 1.f : 0.f;
  }
  float acc[4];
#pragma unroll
  for (int j = 0; j < 4; j++) acc[j] = 0.f;
  const float* ub = U + (size_t)b * 192 * HW;
  for (int ccb = 0; ccb < 12; ccb++) {
    __syncthreads();
    for (int i = tid; i < 576; i += 256) {
      int ccL = i / 36; int rr = i % 36; int tap = rr >> 2; int j = rr & 3;
      wl[i] = wtT[((ccb * 16 + ccL) * 9 + tap) * 64 + o0 + j];
    }
    __syncthreads();
    for (int ccL = 0; ccL < 16; ccL++) {
      const float* p = ub + (ccb * 16 + ccL) * HW;
      float v[9];
#pragma unroll
      for (int t = 0; t < 9; t++) v[t] = p[lin[t]] * msk[t];
      const float* wr = &wl[ccL * 36];
#pragma unroll
      for (int t = 0; t < 9; t++)
#pragma unroll
        for (int j = 0; j < 4; j++) acc[j] += v[t] * wr[t * 4 + j];
    }
  }
  if (act) {
#pragma unroll
    for (int j = 0; j < 4; j++) {
      int o = o0 + j;
      t_out[(size_t)(b * 64 + o) * HW + px] = acc[j] * AtBt[o] + AtBt[64 + o];
    }
  }
}

// ---------------------------------------------------------------------------
// Offset convs: KSxKS conv 64->OC; px-flat, oc-split OSUB via blockIdx.y.
// ---------------------------------------------------------------------------
template <int KS, int PAD, int OC, int CCH, int OSUB>
__global__ __launch_bounds__(256) void k_offconv(
    const float* __restrict__ frames, const float* __restrict__ wT,
    const float* __restrict__ bias, float* __restrict__ dst)
{
  constexpr int K2 = KS * KS;
  __shared__ float wl[CCH * K2 * OSUB];
  const int tid = threadIdx.x;
  const int gpx = blockIdx.x * 256 + tid;
  const bool act = gpx < NPX;
  const int gpe = act ? gpx : 0;
  const int n = gpe / HW, px = gpe % HW;
  const int f = (n / 7) * 8 + (n % 7) + 1;
  const int oc0 = blockIdx.y * OSUB;
  const int y = px / WD, x = px % WD;
  int lin[K2]; float msk[K2];
#pragma unroll
  for (int t = 0; t < K2; t++) {
    int iy = y + t / KS - PAD, ix = x + t % KS - PAD;
    bool ok = iy >= 0 && iy < WD && ix >= 0 && ix < WD;
    lin[t] = min(max(iy, 0), WD - 1) * WD + min(max(ix, 0), WD - 1);
    msk[t] = ok ? 1.f : 0.f;
  }
  float acc[OSUB];
#pragma unroll
  for (int j = 0; j < OSUB; j++) acc[j] = 0.f;
  const float* sb = frames + (size_t)f * 64 * HW;
  for (int cb = 0; cb < 64 / CCH; cb++) {
    __syncthreads();
    for (int i = tid; i < CCH * K2 * OSUB; i += 256) {
      int c = i / (K2 * OSUB); int tap = (i / OSUB) % K2; int j = i % OSUB;
      wl[i] = wT[((cb * CCH + c) * K2 + tap) * OC + oc0 + j];
    }
    __syncthreads();
    for (int cL = 0; cL < CCH; cL++) {
      const float* p = sb + (cb * CCH + cL) * HW;
      float v[K2];
#pragma unroll
      for (int t = 0; t < K2; t++) v[t] = p[lin[t]] * msk[t];
      const float* wr = &wl[cL * K2 * OSUB];
#pragma unroll
      for (int t = 0; t < K2; t++)
#pragma unroll
        for (int j = 0; j < OSUB; j++) acc[j] += v[t] * wr[t * OSUB + j];
    }
  }
  if (act) {
#pragma unroll
    for (int j = 0; j < OSUB; j++)
      dst[(size_t)(n * OC + oc0 + j) * HW + px] = acc[j] + bias[oc0 + j];
  }
}

// ---------------------------------------------------------------------------
// Deformable conv on px-major xT. c-split via blockIdx.y (gridDim.y planes),
// each split block OWNS partial plane P_s: deform3 writes, deform5 adds.
// Bilinear: per (k, 4c) four float4 corner loads + 256 FMAs. No atomics.
// ---------------------------------------------------------------------------
template <int KS, int PAD, bool ACCUM>
__global__ __launch_bounds__(256) void k_deform(
    const float* __restrict__ xT, const float* __restrict__ offs,
    const float* __restrict__ wT, float* __restrict__ dsum,
    float* __restrict__ pext)
{
  constexpr int K2 = KS * KS;
  __shared__ float wl[64 * 64];             // up to 16 KB, NC*64 used
  const int tid = threadIdx.x;
  const int s = blockIdx.y;
  const int NC = 64 / gridDim.y;
  const int c0 = s * NC;
  float* P = (s == 0) ? dsum : pext + (size_t)(s - 1) * PLANE;
  const int gpx = blockIdx.x * 256 + tid;
  const bool act = gpx < NPX;
  const int gpe = act ? gpx : 0;
  const int n = gpe / HW, px = gpe % HW;
  const int y = px / WD, x = px % WD;
  const float* pt = xT + (size_t)n * HW * 64;
  const float* ob = offs + (size_t)n * (2 * K2) * HW + px;
  float acc[64];
#pragma unroll
  for (int j = 0; j < 64; j++) acc[j] = 0.f;
  for (int k = 0; k < K2; k++) {
    __syncthreads();
    for (int i = tid; i < NC * 16; i += 256)      // NC*64 floats as float4
      ((float4*)wl)[i] = *(const float4*)(wT + k * 4096 + c0 * 64 + i * 4);
    __syncthreads();
    float offy = ob[(2 * k) * HW];
    float offx = ob[(2 * k + 1) * HW];
    float py = (float)(y + k / KS - PAD) + offy;
    float pxx = (float)(x + k % KS - PAD) + offx;
    float fy = floorf(py), fx = floorf(pxx);
    int y0 = (int)fy, x0 = (int)fx;
    float ly = py - fy, lx = pxx - fx;
    int y1 = y0 + 1, x1 = x0 + 1;
    float vy0 = (y0 >= 0 && y0 < WD) ? 1.f : 0.f;
    float vy1 = (y1 >= 0 && y1 < WD) ? 1.f : 0.f;
    float vx0 = (x0 >= 0 && x0 < WD) ? 1.f : 0.f;
    float vx1 = (x1 >= 0 && x1 < WD) ? 1.f : 0.f;
    float w00 = (1.f - ly) * (1.f - lx) * vy0 * vx0;
    float w01 = (1.f - ly) * lx * vy0 * vx1;
    float w10 = ly * (1.f - lx) * vy1 * vx0;
    float w11 = ly * lx * vy1 * vx1;
    int cy0 = min(max(y0, 0), WD - 1), cy1 = min(max(y1, 0), WD - 1);
    int cx0 = min(max(x0, 0), WD - 1), cx1 = min(max(x1, 0), WD - 1);
    const float* p00 = pt + (cy0 * WD + cx0) * 64 + c0;
    const float* p01 = pt + (cy0 * WD + cx1) * 64 + c0;
    const float* p10 = pt + (cy1 * WD + cx0) * 64 + c0;
    const float* p11 = pt + (cy1 * WD + cx1) * 64 + c0;
    for (int cb = 0; cb < NC; cb += 4) {
      float4 a = *(const float4*)(p00 + cb);
      float4 b = *(const float4*)(p01 + cb);
      float4 c4 = *(const float4*)(p10 + cb);
      float4 d = *(const float4*)(p11 + cb);
      float g0 = a.x * w00 + b.x * w01 + c4.x * w10 + d.x * w11;
      float g1 = a.y * w00 + b.y * w01 + c4.y * w10 + d.y * w11;
      float g2 = a.z * w00 + b.z * w01 + c4.z * w10 + d.z * w11;
      float g3 = a.w * w00 + b.w * w01 + c4.w * w10 + d.w * w11;
      const float* wr = &wl[cb * 64];
#pragma unroll
      for (int j = 0; j < 64; j++) acc[j] += g0 * wr[j];
      wr += 64;
#pragma unroll
      for (int j = 0; j < 64; j++) acc[j] += g1 * wr[j];
      wr += 64;
#pragma unroll
      for (int j = 0; j < 64; j++) acc[j] += g2 * wr[j];
      wr += 64;
#pragma unroll
      for (int j = 0; j < 64; j++) acc[j] += g3 * wr[j];
    }
  }
  if (act) {
    float* dp = P + (size_t)n * 64 * HW + px;
#pragma unroll
    for (int j = 0; j < 64; j++) {
      if (ACCUM) dp[j * HW] += acc[j];
      else dp[j * HW] = acc[j];
    }
  }
}

// ---------------------------------------------------------------------------
// maxpool 3x3 + 1x1 conv (BN folded) + partial-plane sum + diff epilogue.
// ---------------------------------------------------------------------------
__global__ __launch_bounds__(256) void k_davg_diff(
    const float* __restrict__ frames, const float* __restrict__ c1T,
    const float* __restrict__ B3, float* __restrict__ dsum,
    const float* __restrict__ pext, int nsplit)
{
  __shared__ float wl[64 * 32];
  const int tid = threadIdx.x;
  const int o0 = blockIdx.y * 32;
  for (int i = tid; i < 512; i += 256) {
    int c = i >> 3, q = i & 7;
    ((float4*)wl)[i] = *(const float4*)(c1T + c * 64 + o0 + q * 4);
  }
  __syncthreads();
  const int gpx = blockIdx.x * 256 + tid;
  const bool act = gpx < NPX;
  const int gpe = act ? gpx : 0;
  const int n = gpe / HW, px = gpe % HW;
  const int b = n / 7, t = n % 7;
  const int fpost = b * 8 + t + 1, fpre = b * 8 + t;
  const int y = px / WD, x = px % WD;
  int lin[9]; bool okm[9];
#pragma unroll
  for (int t2 = 0; t2 < 9; t2++) {
    int iy = y + t2 / 3 - 1, ix = x + t2 % 3 - 1;
    okm[t2] = iy >= 0 && iy < WD && ix >= 0 && ix < WD;
    lin[t2] = min(max(iy, 0), WD - 1) * WD + min(max(ix, 0), WD - 1);
  }
  float acc[32];
#pragma unroll
  for (int j = 0; j < 32; j++) acc[j] = 0.f;
  const float* sb = frames + (size_t)fpost * 64 * HW;
  for (int c = 0; c < 64; c++) {
    const float* p = sb + c * HW;
    float m = -1e30f;
#pragma unroll
    for (int t2 = 0; t2 < 9; t2++) {
      float v = okm[t2] ? p[lin[t2]] : -1e30f;
      m = fmaxf(m, v);
    }
    const float* wr = &wl[c * 32];
#pragma unroll
    for (int j = 0; j < 32; j++) acc[j] += m * wr[j];
  }
  if (act) {
    const float* xpre = frames + (size_t)fpre * 64 * HW + px;
    float* dp = dsum + (size_t)n * 64 * HW + px;
#pragma unroll
    for (int j = 0; j < 32; j++) {
      int o = o0 + j;
      float d3sum = dp[o * HW];
      for (int s = 1; s < nsplit; s++)
        d3sum += pext[(size_t)(s - 1) * PLANE + (size_t)n * 64 * HW + o * HW + px];
      float d = d3sum + (acc[j] + B3[o]) - 3.f * xpre[o * HW];
      dp[o * HW] = fabsf(d);
    }
  }
}

// ---------------------------------------------------------------------------
// Spatial mean of cat = [diff frames | t_out] per (nt, c).
// ---------------------------------------------------------------------------
__global__ void k_gmean(const float* __restrict__ dsum,
                        const float* __restrict__ t_out,
                        float* __restrict__ gmean)
{
  const int nt = blockIdx.x, c = blockIdx.y;
  const int b = nt >> 3, tt = nt & 7;
  const float* p = (tt < 7) ? (dsum + (size_t)((b * 7 + tt) * 64 + c) * HW)
                            : (t_out + (size_t)(b * 64 + c) * HW);
  const int tid = threadIdx.x;
  float s = 0.f;
  for (int i = tid; i < HW; i += 64) s += p[i];
#pragma unroll
  for (int o = 32; o > 0; o >>= 1) s += __shfl_down(s, o, 64);
  if (tid == 0) gmean[nt * 64 + c] = s * (1.f / HW);
}

// ---------------------------------------------------------------------------
// Gate: 1x1 conv 64->256 + sigmoid; store mult.
// ---------------------------------------------------------------------------
__global__ __launch_bounds__(256) void k_gate(
    const float* __restrict__ gmean, const float* __restrict__ gwT,
    const float* __restrict__ Bg, float* __restrict__ mult)
{
  __shared__ float gm[64];
  const int nt = blockIdx.x, co = threadIdx.x;
  if (co < 64) gm[co] = gmean[nt * 64 + co];
  __syncthreads();
  float a = 0.f;
#pragma unroll 8
  for (int c = 0; c < 64; c++) a += gm[c] * gwT[c * 256 + co];
  float pre = a + Bg[co];
  mult[nt * 256 + co] = 0.5f + 1.f / (1.f + expf(-pre));
}

// ---------------------------------------------------------------------------
// out = x * mult[nt,co]
// ---------------------------------------------------------------------------
__global__ void k_apply(const float* __restrict__ x,
                        const float* __restrict__ mult,
                        float* __restrict__ outp)
{
  const int i = blockIdx.x * 256 + threadIdx.x;
  const int plane = i / 196;
  const float m = mult[plane];
  float4 v = ((const float4*)x)[i];
  v.x *= m; v.y *= m; v.z *= m; v.w *= m;
  ((float4*)outp)[i] = v;
}

// ---------------------------------------------------------------------------
extern "C" void kernel_launch(void* const* d_in, const int* in_sizes, int n_in,
                              void* d_out, int out_size, void* d_ws, size_t ws_size,
                              hipStream_t stream)
{
  const float* x       = (const float*)d_in[0];
  const float* w_down  = (const float*)d_in[1];
  const float* b_down  = (const float*)d_in[2];
  const float* bn1_g   = (const float*)d_in[3];
  const float* bn1_b   = (const float*)d_in[4];
  const float* bn1_m   = (const float*)d_in[5];
  const float* bn1_v   = (const float*)d_in[6];
  const float* tconv_w = (const float*)d_in[7];
  const float* tconv_b = (const float*)d_in[8];
  const float* bnt_g   = (const float*)d_in[9];
  const float* bnt_b   = (const float*)d_in[10];
  const float* bnt_m   = (const float*)d_in[11];
  const float* bnt_v   = (const float*)d_in[12];
  const float* off3_w  = (const float*)d_in[13];
  const float* off3_b  = (const float*)d_in[14];
  const float* def3_w  = (const float*)d_in[15];
  const float* off5_w  = (const float*)d_in[16];
  const float* off5_b  = (const float*)d_in[17];
  const float* def5_w  = (const float*)d_in[18];
  const float* conv1_w = (const float*)d_in[19];
  const float* conv1_b = (const float*)d_in[20];
  const float* bn3_g   = (const float*)d_in[21];
  const float* bn3_b   = (const float*)d_in[22];
  const float* bn3_m   = (const float*)d_in[23];
  const float* bn3_v   = (const float*)d_in[24];
  const float* conv_w  = (const float*)d_in[25];
  const float* conv_b  = (const float*)d_in[26];
  const float* bn2_g   = (const float*)d_in[27];
  const float* bn2_b   = (const float*)d_in[28];
  const float* bn2_m   = (const float*)d_in[29];
  const float* bn2_v   = (const float*)d_in[30];

  float* ws = (float*)d_ws;
  float* out_b  = ws; ws += 64 * 64 * HW;
  float* U      = ws; ws += 8 * 192 * HW;
  float* t_out  = ws; ws += 8 * 64 * HW;
  float* off3b  = ws; ws += 56 * 18 * HW;
  float* off5b  = ws; ws += 56 * 50 * HW;
  float* dsum   = ws; ws += PLANE;
  float* gmean  = ws; ws += 64 * 64;
  float* multb  = ws; ws += 64 * 256;
  float* wdownT = ws; ws += 256 * 64;
  float* bias1  = ws; ws += 64;
  float* wtT    = ws; ws += 192 * 9 * 64;
  float* AtBt   = ws; ws += 128;
  float* off3T  = ws; ws += 64 * 9 * 18;
  float* off5T  = ws; ws += 64 * 25 * 50;
  float* def3T  = ws; ws += 9 * 64 * 64;
  float* def5T  = ws; ws += 25 * 64 * 64;
  float* c1T    = ws; ws += 64 * 64;
  float* B3     = ws; ws += 64;
  float* gwT    = ws; ws += 64 * 256;
  float* Bg     = ws; ws += 256;
  float* xT     = ws; ws += PLANE;          // px-major post frames
  float* pext   = ws;                       // up to 3 extra partial planes

  // choose c-split factor from available workspace (constant across calls)
  const size_t base = (size_t)(ws - (float*)d_ws);
  const size_t wsf = ws_size / sizeof(float);
  int CSPL = 1;
  if (wsf >= base + 3 * (size_t)PLANE) CSPL = 4;
  else if (wsf >= base + 1 * (size_t)PLANE) CSPL = 2;

  k_prep<<<256, 256, 0, stream>>>(
      w_down, b_down, bn1_g, bn1_b, bn1_m, bn1_v,
      tconv_w, tconv_b, bnt_g, bnt_b, bnt_m, bnt_v,
      off3_w, def3_w, off5_w, def5_w,
      conv1_w, conv1_b, bn3_g, bn3_b, bn3_m, bn3_v,
      conv_w, conv_b, bn2_g, bn2_b, bn2_m, bn2_v,
      wdownT, bias1, wtT, AtBt, off3T, off5T, def3T, def5T,
      c1T, B3, gwT, Bg);

  k_down<<<dim3(196, 2), 256, 0, stream>>>(x, wdownT, bias1, out_b);
  k_xpose<<<dim3(56, 13), 256, 0, stream>>>(out_b, xT);
  k_makeU<<<1568, 256, 0, stream>>>(out_b, U);
  k_tconv<<<dim3(8, 4, 16), 256, 0, stream>>>(U, wtT, AtBt, t_out);
  k_offconv<3, 1, 18, 16, 6><<<dim3(PXBLK, 3), 256, 0, stream>>>(out_b, off3T, off3_b, off3b);
  k_offconv<5, 2, 50, 8, 10><<<dim3(PXBLK, 5), 256, 0, stream>>>(out_b, off5T, off5_b, off5b);
  k_deform<3, 1, false><<<dim3(PXBLK, CSPL), 256, 0, stream>>>(xT, off3b, def3T, dsum, pext);
  k_deform<5, 2, true><<<dim3(PXBLK, CSPL), 256, 0, stream>>>(xT, off5b, def5T, dsum, pext);
  k_davg_diff<<<dim3(PXBLK, 2), 256, 0, stream>>>(out_b, c1T, B3, dsum, pext, CSPL);
  k_gmean<<<dim3(64, 64), 64, 0, stream>>>(dsum, t_out, gmean);
  k_gate<<<64, 256, 0, stream>>>(gmean, gwT, Bg, multb);
  k_apply<<<12544, 256, 0, stream>>>(x, multb, (float*)d_out);
}

// Round 5
// 713.976 us; speedup vs baseline: 3.2131x; 1.4239x over previous
//
#include <hip/hip_runtime.h>
#include <hip/hip_bf16.h>

#define HW 784
#define WD 28
#define NPX (56 * HW)          // 43904 deform/offconv pixels
#define PXBLK 172              // ceil(43904/256)
#define PLANE (56 * 64 * HW)   // 2,809,856 floats: one partial plane
#define PADPX 1024             // 32x32 padded spatial (halo 2)

using short8 = __attribute__((ext_vector_type(8))) short;
using f32x4  = __attribute__((ext_vector_type(4))) float;

// ---------------------------------------------------------------------------
// Prep: fold BN into transposed weight layouts + MFMA-fragment-order bf16
// weights for the offset convs.
// wBs[tap][chunk][ntile][lane][j] (bf16): B[k=chunk*32+(lane>>4)*8+j][oc=ntile*16+(lane&15)]
// ---------------------------------------------------------------------------
__global__ void k_prep(
    const float* __restrict__ w_down, const float* __restrict__ b_down,
    const float* __restrict__ bn1_g, const float* __restrict__ bn1_b,
    const float* __restrict__ bn1_m, const float* __restrict__ bn1_v,
    const float* __restrict__ tconv_w, const float* __restrict__ tconv_b,
    const float* __restrict__ bnt_g, const float* __restrict__ bnt_b,
    const float* __restrict__ bnt_m, const float* __restrict__ bnt_v,
    const float* __restrict__ off3_w, const float* __restrict__ def3_w,
    const float* __restrict__ off5_w, const float* __restrict__ def5_w,
    const float* __restrict__ conv1_w, const float* __restrict__ conv1_b,
    const float* __restrict__ bn3_g, const float* __restrict__ bn3_b,
    const float* __restrict__ bn3_m, const float* __restrict__ bn3_v,
    const float* __restrict__ conv_w, const float* __restrict__ conv_b,
    const float* __restrict__ bn2_g, const float* __restrict__ bn2_b,
    const float* __restrict__ bn2_m, const float* __restrict__ bn2_v,
    float* __restrict__ wdownT, float* __restrict__ bias1,
    float* __restrict__ wtT, float* __restrict__ AtBt,
    __hip_bfloat16* __restrict__ wBs3, __hip_bfloat16* __restrict__ wBs5,
    float* __restrict__ def3T, float* __restrict__ def5T,
    float* __restrict__ c1T, float* __restrict__ B3,
    float* __restrict__ gwT, float* __restrict__ Bg)
{
  const int tid = blockIdx.x * blockDim.x + threadIdx.x;
  const int nth = gridDim.x * blockDim.x;
  for (int i = tid; i < 256 * 64; i += nth) {
    int c = i >> 6, cr = i & 63;
    float s = bn1_g[cr] / sqrtf(bn1_v[cr] + 1e-5f);
    wdownT[i] = w_down[cr * 256 + c] * s;
  }
  for (int i = tid; i < 64; i += nth) {
    float s = bn1_g[i] / sqrtf(bn1_v[i] + 1e-5f);
    bias1[i] = (b_down[i] - bn1_m[i]) * s + bn1_b[i];
  }
  for (int i = tid; i < 192 * 9 * 64; i += nth) {
    int cc = i / (9 * 64); int tap = (i / 64) % 9; int o = i & 63;
    int dt = cc >> 6, c = cc & 63;
    wtT[i] = tconv_w[o * 1728 + c * 27 + dt * 9 + tap];
  }
  for (int i = tid; i < 64; i += nth) {
    float s = bnt_g[i] / sqrtf(bnt_v[i] + 1e-5f);
    AtBt[i] = s * 0.125f;
    AtBt[64 + i] = (tconv_b[i] - bnt_m[i]) * s + bnt_b[i];
  }
  // off3 MFMA B-frags: K2=9, NT=2 (ocpad 32). total 9*2*2*512 = 18432
  for (int i = tid; i < 9 * 2 * 2 * 512; i += nth) {
    int j = i & 7; int lane = (i >> 3) & 63;
    int rest = i >> 9; int nt = rest % 2; rest /= 2;
    int chunk = rest & 1; int tap = rest >> 1;
    int c = chunk * 32 + ((lane >> 4) << 3) + j;
    int oc = nt * 16 + (lane & 15);
    float v = (oc < 18) ? off3_w[oc * 576 + c * 9 + tap] : 0.f;
    wBs3[i] = __float2bfloat16(v);
  }
  // off5 MFMA B-frags: K2=25, NT=4 (ocpad 64). total 25*2*4*512 = 102400
  for (int i = tid; i < 25 * 2 * 4 * 512; i += nth) {
    int j = i & 7; int lane = (i >> 3) & 63;
    int rest = i >> 9; int nt = rest % 4; rest /= 4;
    int chunk = rest & 1; int tap = rest >> 1;
    int c = chunk * 32 + ((lane >> 4) << 3) + j;
    int oc = nt * 16 + (lane & 15);
    float v = (oc < 50) ? off5_w[oc * 1600 + c * 25 + tap] : 0.f;
    wBs5[i] = __float2bfloat16(v);
  }
  for (int i = tid; i < 9 * 64 * 64; i += nth) {
    int k = i >> 12; int c = (i >> 6) & 63; int o = i & 63;
    def3T[i] = def3_w[o * 576 + c * 9 + k];
  }
  for (int i = tid; i < 25 * 64 * 64; i += nth) {
    int k = i >> 12; int c = (i >> 6) & 63; int o = i & 63;
    def5T[i] = def5_w[o * 1600 + c * 25 + k];
  }
  for (int i = tid; i < 64 * 64; i += nth) {
    int c = i >> 6, o = i & 63;
    float s = bn3_g[o] / sqrtf(bn3_v[o] + 1e-5f);
    c1T[i] = conv1_w[o * 64 + c] * s;
  }
  for (int i = tid; i < 64; i += nth) {
    float s = bn3_g[i] / sqrtf(bn3_v[i] + 1e-5f);
    B3[i] = (conv1_b[i] - bn3_m[i]) * s + bn3_b[i];
  }
  for (int i = tid; i < 64 * 256; i += nth) {
    int c = i >> 8, co = i & 255;
    float s = bn2_g[co] / sqrtf(bn2_v[co] + 1e-5f);
    gwT[i] = conv_w[co * 64 + c] * s;
  }
  for (int i = tid; i < 256; i += nth) {
    float s = bn2_g[i] / sqrtf(bn2_v[i] + 1e-5f);
    Bg[i] = (conv_b[i] - bn2_m[i]) * s + bn2_b[i];
  }
}

// ---------------------------------------------------------------------------
// Zero the padded bf16 image (halo must be 0 every call; ws is re-poisoned).
// 56*1024*64 bf16 = 458752 float4.
// ---------------------------------------------------------------------------
__global__ void k_zerob(float4* __restrict__ p)
{
  p[blockIdx.x * 256 + threadIdx.x] = make_float4(0.f, 0.f, 0.f, 0.f);
}

// ---------------------------------------------------------------------------
// 1x1 down conv (256->64) + BN fold. px-flat grid (196, o-split 2).
// ---------------------------------------------------------------------------
__global__ __launch_bounds__(256) void k_down(
    const float* __restrict__ x, const float* __restrict__ wdownT,
    const float* __restrict__ bias1, float* __restrict__ out)
{
  __shared__ float wl[256 * 32];            // 32 KB
  const int tid = threadIdx.x;
  const int o0 = blockIdx.y * 32;
  for (int i = tid; i < 2048; i += 256) {
    int c = i >> 3, q = i & 7;
    ((float4*)wl)[i] = *(const float4*)(wdownT + c * 64 + o0 + q * 4);
  }
  __syncthreads();
  const int gpx = blockIdx.x * 256 + tid;   // < 50176 exact
  const int f = gpx / HW, px = gpx % HW;
  const float* xp = x + (size_t)f * 256 * HW + px;
  float acc[32];
#pragma unroll
  for (int j = 0; j < 32; j++) acc[j] = 0.f;
#pragma unroll 4
  for (int c = 0; c < 256; c++) {
    float xv = xp[c * HW];
    const float* wr = &wl[c * 32];
#pragma unroll
    for (int j = 0; j < 32; j++) acc[j] += xv * wr[j];
  }
  float* op = out + (size_t)f * 64 * HW + px;
#pragma unroll
  for (int j = 0; j < 32; j++) op[(o0 + j) * HW] = acc[j] + bias1[o0 + j];
}

// ---------------------------------------------------------------------------
// Transpose post frames to px-major: xT[n][px][c] (f32, for deform) and
// padded bf16 xTbP[n][(py+2)*32+(px+2)][c] (for MFMA offconvs).
// ---------------------------------------------------------------------------
__global__ __launch_bounds__(256) void k_xpose(
    const float* __restrict__ out_b, float* __restrict__ xT,
    __hip_bfloat16* __restrict__ xTbP)
{
  __shared__ float t[64 * 65];
  const int tid = threadIdx.x;
  const int lane = tid & 63, grp = tid >> 6;
  const int n = blockIdx.x;
  const int f = (n / 7) * 8 + (n % 7) + 1;
  const int px0 = blockIdx.y * 64;
  const float* sb = out_b + (size_t)f * 64 * HW;
#pragma unroll
  for (int c = grp; c < 64; c += 4) {
    int px = px0 + lane;
    t[c * 65 + lane] = (px < HW) ? sb[c * HW + px] : 0.f;
  }
  __syncthreads();
#pragma unroll
  for (int r = grp; r < 64; r += 4) {
    int px = px0 + r;
    if (px < HW) {
      float v = t[lane * 65 + r];
      xT[((size_t)n * HW + px) * 64 + lane] = v;
      int py = px / WD, pxc = px % WD;
      xTbP[((size_t)n * PADPX + (py + 2) * 32 + (pxc + 2)) * 64 + lane] =
          __float2bfloat16(v);
    }
  }
}

// ---------------------------------------------------------------------------
// U planes for collapsed temporal conv.
// ---------------------------------------------------------------------------
__global__ void k_makeU(const float* __restrict__ out, float* __restrict__ U)
{
  const int idx = blockIdx.x * 256 + threadIdx.x;
  const int b = idx / (64 * HW);
  const int r = idx % (64 * HW);
  const float* p = out + (size_t)b * 8 * 64 * HW + r;
  float v0 = p[0];
  float s = v0, v = v0;
#pragma unroll
  for (int t = 1; t < 8; t++) { v = p[t * 64 * HW]; s += v; }
  float* u = U + (size_t)b * 192 * HW + r;
  u[0] = s - v;
  u[64 * HW] = s;
  u[128 * HW] = s - v0;
}

// ---------------------------------------------------------------------------
// Collapsed temporal conv: 3x3, 192->64. o-groups of 4 (16 z-blocks).
// ---------------------------------------------------------------------------
__global__ __launch_bounds__(256) void k_tconv(
    const float* __restrict__ U, const float* __restrict__ wtT,
    const float* __restrict__ AtBt, float* __restrict__ t_out)
{
  __shared__ float wl[16 * 9 * 4];
  const int tid = threadIdx.x;
  const int b = blockIdx.x;
  const int px = blockIdx.y * 256 + tid;
  const int o0 = blockIdx.z * 4;
  const bool act = px < HW;
  const int pxe = act ? px : 0;
  const int y = pxe / WD, x = pxe % WD;
  int lin[9]; float msk[9];
#pragma unroll
  for (int t = 0; t < 9; t++) {
    int iy = y + t / 3 - 1, ix = x + t % 3 - 1;
    bool ok = iy >= 0 && iy < WD && ix >= 0 && ix < WD;
    lin[t] = min(max(iy, 0), WD - 1) * WD + min(max(ix, 0), WD - 1);
    msk[t] = ok ? 1.f : 0.f;
  }
  float acc[4];
#pragma unroll
  for (int j = 0; j < 4; j++) acc[j] = 0.f;
  const float* ub = U + (size_t)b * 192 * HW;
  for (int ccb = 0; ccb < 12; ccb++) {
    __syncthreads();
    for (int i = tid; i < 576; i += 256) {
      int ccL = i / 36; int rr = i % 36; int tap = rr >> 2; int j = rr & 3;
      wl[i] = wtT[((ccb * 16 + ccL) * 9 + tap) * 64 + o0 + j];
    }
    __syncthreads();
    for (int ccL = 0; ccL < 16; ccL++) {
      const float* p = ub + (ccb * 16 + ccL) * HW;
      float v[9];
#pragma unroll
      for (int t = 0; t < 9; t++) v[t] = p[lin[t]] * msk[t];
      const float* wr = &wl[ccL * 36];
#pragma unroll
      for (int t = 0; t < 9; t++)
#pragma unroll
        for (int j = 0; j < 4; j++) acc[j] += v[t] * wr[t * 4 + j];
    }
  }
  if (act) {
#pragma unroll
    for (int j = 0; j < 4; j++) {
      int o = o0 + j;
      t_out[(size_t)(b * 64 + o) * HW + px] = acc[j] * AtBt[o] + AtBt[64 + o];
    }
  }
}

// ---------------------------------------------------------------------------
// Offset convs as implicit-GEMM bf16 MFMA (16x16x32).
// Block = 64 px (4 waves x 16 rows) x OCpad (NT*16). K = K2*64 over
// (tap, c-chunk). A from padded px-major bf16 image (borders = exact 0),
// B from pre-swizzled frag-order weights staged in LDS (1 ds_read_b128/frag).
// Epilogue via LDS transpose for coalesced f32 stores.
// ---------------------------------------------------------------------------
template <int KS, int PAD, int OC, int NT, int TAPBLK>
__global__ __launch_bounds__(256) void k_offconv_mfma(
    const __hip_bfloat16* __restrict__ xTbP,
    const __hip_bfloat16* __restrict__ wBs,
    const float* __restrict__ bias, float* __restrict__ dst)
{
  constexpr int K2 = KS * KS;
  __shared__ short bs[TAPBLK * NT * 1024];   // B frags, 2*NT KB per tap
  __shared__ float ct[NT * 16 * 65];         // C tile [ocpad][px(64)+pad]
  const int tid = threadIdx.x;
  const int w = tid >> 6, lane = tid & 63;
  const int quad = lane >> 4, mrow = lane & 15;
  const int gpx = blockIdx.x * 64 + w * 16 + mrow;   // A-row pixel
  const int n = gpx / HW, px = gpx % HW;
  const int y = px / WD, x = px % WD;
  const short* xb = (const short*)xTbP + ((size_t)n * PADPX) * 64;
  f32x4 acc[NT];
#pragma unroll
  for (int nt = 0; nt < NT; nt++) acc[nt] = (f32x4){0.f, 0.f, 0.f, 0.f};

  for (int tb = 0; tb < K2; tb += TAPBLK) {
    __syncthreads();
    for (int i = tid; i < TAPBLK * NT * 128; i += 256)
      ((float4*)bs)[i] = ((const float4*)(wBs + (size_t)tb * NT * 1024))[i];
    __syncthreads();
#pragma unroll
    for (int t2 = 0; t2 < TAPBLK; t2++) {
      int tap = tb + t2;
      if (K2 % TAPBLK != 0 && tap >= K2) break;
      int ty = tap / KS, tx = tap % KS;
      int sp = (y + ty + (2 - PAD)) * 32 + (x + tx + (2 - PAD));
      const short* ap = xb + sp * 64 + quad * 8;
      short8 a0 = *(const short8*)(ap);
      short8 a1 = *(const short8*)(ap + 32);
      const short* bp = bs + t2 * NT * 1024;
#pragma unroll
      for (int nt = 0; nt < NT; nt++) {
        short8 b0 = *(const short8*)(bp + nt * 512 + lane * 8);
        acc[nt] = __builtin_amdgcn_mfma_f32_16x16x32_bf16(a0, b0, acc[nt], 0, 0, 0);
      }
#pragma unroll
      for (int nt = 0; nt < NT; nt++) {
        short8 b1 = *(const short8*)(bp + (NT + nt) * 512 + lane * 8);
        acc[nt] = __builtin_amdgcn_mfma_f32_16x16x32_bf16(a1, b1, acc[nt], 0, 0, 0);
      }
    }
  }
  // C/D frag: col(oc) = lane&15, row(px) = quad*4 + reg
  __syncthreads();
#pragma unroll
  for (int nt = 0; nt < NT; nt++) {
    int oc_l = nt * 16 + mrow;
#pragma unroll
    for (int reg = 0; reg < 4; reg++) {
      int pxr = w * 16 + quad * 4 + reg;
      ct[oc_l * 65 + pxr] = acc[nt][reg];
    }
  }
  __syncthreads();
  for (int i = tid; i < OC * 64; i += 256) {
    int oc = i >> 6, p2 = i & 63;
    int g2 = blockIdx.x * 64 + p2;
    int n2 = g2 / HW, px2 = g2 % HW;
    dst[((size_t)n2 * OC + oc) * HW + px2] = ct[oc * 65 + p2] + bias[oc];
  }
}

// ---------------------------------------------------------------------------
// Deformable conv on px-major xT. c-split via blockIdx.y (gridDim.y planes),
// each split block OWNS partial plane P_s: deform3 writes, deform5 adds.
// Bilinear: per (k, 4c) four float4 corner loads + 256 FMAs. No atomics.
// ---------------------------------------------------------------------------
template <int KS, int PAD, bool ACCUM>
__global__ __launch_bounds__(256) void k_deform(
    const float* __restrict__ xT, const float* __restrict__ offs,
    const float* __restrict__ wT, float* __restrict__ dsum,
    float* __restrict__ pext)
{
  constexpr int K2 = KS * KS;
  __shared__ float wl[64 * 64];             // up to 16 KB, NC*64 used
  const int tid = threadIdx.x;
  const int s = blockIdx.y;
  const int NC = 64 / gridDim.y;
  const int c0 = s * NC;
  float* P = (s == 0) ? dsum : pext + (size_t)(s - 1) * PLANE;
  const int gpx = blockIdx.x * 256 + tid;
  const bool act = gpx < NPX;
  const int gpe = act ? gpx : 0;
  const int n = gpe / HW, px = gpe % HW;
  const int y = px / WD, x = px % WD;
  const float* pt = xT + (size_t)n * HW * 64;
  const float* ob = offs + (size_t)n * (2 * K2) * HW + px;
  float acc[64];
#pragma unroll
  for (int j = 0; j < 64; j++) acc[j] = 0.f;
  for (int k = 0; k < K2; k++) {
    __syncthreads();
    for (int i = tid; i < NC * 16; i += 256)      // NC*64 floats as float4
      ((float4*)wl)[i] = *(const float4*)(wT + k * 4096 + c0 * 64 + i * 4);
    __syncthreads();
    float offy = ob[(2 * k) * HW];
    float offx = ob[(2 * k + 1) * HW];
    float py = (float)(y + k / KS - PAD) + offy;
    float pxx = (float)(x + k % KS - PAD) + offx;
    float fy = floorf(py), fx = floorf(pxx);
    int y0 = (int)fy, x0 = (int)fx;
    float ly = py - fy, lx = pxx - fx;
    int y1 = y0 + 1, x1 = x0 + 1;
    float vy0 = (y0 >= 0 && y0 < WD) ? 1.f : 0.f;
    float vy1 = (y1 >= 0 && y1 < WD) ? 1.f : 0.f;
    float vx0 = (x0 >= 0 && x0 < WD) ? 1.f : 0.f;
    float vx1 = (x1 >= 0 && x1 < WD) ? 1.f : 0.f;
    float w00 = (1.f - ly) * (1.f - lx) * vy0 * vx0;
    float w01 = (1.f - ly) * lx * vy0 * vx1;
    float w10 = ly * (1.f - lx) * vy1 * vx0;
    float w11 = ly * lx * vy1 * vx1;
    int cy0 = min(max(y0, 0), WD - 1), cy1 = min(max(y1, 0), WD - 1);
    int cx0 = min(max(x0, 0), WD - 1), cx1 = min(max(x1, 0), WD - 1);
    const float* p00 = pt + (cy0 * WD + cx0) * 64 + c0;
    const float* p01 = pt + (cy0 * WD + cx1) * 64 + c0;
    const float* p10 = pt + (cy1 * WD + cx0) * 64 + c0;
    const float* p11 = pt + (cy1 * WD + cx1) * 64 + c0;
    for (int cb = 0; cb < NC; cb += 4) {
      float4 a = *(const float4*)(p00 + cb);
      float4 b = *(const float4*)(p01 + cb);
      float4 c4 = *(const float4*)(p10 + cb);
      float4 d = *(const float4*)(p11 + cb);
      float g0 = a.x * w00 + b.x * w01 + c4.x * w10 + d.x * w11;
      float g1 = a.y * w00 + b.y * w01 + c4.y * w10 + d.y * w11;
      float g2 = a.z * w00 + b.z * w01 + c4.z * w10 + d.z * w11;
      float g3 = a.w * w00 + b.w * w01 + c4.w * w10 + d.w * w11;
      const float* wr = &wl[cb * 64];
#pragma unroll
      for (int j = 0; j < 64; j++) acc[j] += g0 * wr[j];
      wr += 64;
#pragma unroll
      for (int j = 0; j < 64; j++) acc[j] += g1 * wr[j];
      wr += 64;
#pragma unroll
      for (int j = 0; j < 64; j++) acc[j] += g2 * wr[j];
      wr += 64;
#pragma unroll
      for (int j = 0; j < 64; j++) acc[j] += g3 * wr[j];
    }
  }
  if (act) {
    float* dp = P + (size_t)n * 64 * HW + px;
#pragma unroll
    for (int j = 0; j < 64; j++) {
      if (ACCUM) dp[j * HW] += acc[j];
      else dp[j * HW] = acc[j];
    }
  }
}

// ---------------------------------------------------------------------------
// maxpool 3x3 + 1x1 conv (BN folded) + partial-plane sum + diff epilogue.
// ---------------------------------------------------------------------------
__global__ __launch_bounds__(256) void k_davg_diff(
    const float* __restrict__ frames, const float* __restrict__ c1T,
    const float* __restrict__ B3, float* __restrict__ dsum,
    const float* __restrict__ pext, int nsplit)
{
  __shared__ float wl[64 * 32];
  const int tid = threadIdx.x;
  const int o0 = blockIdx.y * 32;
  for (int i = tid; i < 512; i += 256) {
    int c = i >> 3, q = i & 7;
    ((float4*)wl)[i] = *(const float4*)(c1T + c * 64 + o0 + q * 4);
  }
  __syncthreads();
  const int gpx = blockIdx.x * 256 + tid;
  const bool act = gpx < NPX;
  const int gpe = act ? gpx : 0;
  const int n = gpe / HW, px = gpe % HW;
  const int b = n / 7, t = n % 7;
  const int fpost = b * 8 + t + 1, fpre = b * 8 + t;
  const int y = px / WD, x = px % WD;
  int lin[9]; bool okm[9];
#pragma unroll
  for (int t2 = 0; t2 < 9; t2++) {
    int iy = y + t2 / 3 - 1, ix = x + t2 % 3 - 1;
    okm[t2] = iy >= 0 && iy < WD && ix >= 0 && ix < WD;
    lin[t2] = min(max(iy, 0), WD - 1) * WD + min(max(ix, 0), WD - 1);
  }
  float acc[32];
#pragma unroll
  for (int j = 0; j < 32; j++) acc[j] = 0.f;
  const float* sb = frames + (size_t)fpost * 64 * HW;
  for (int c = 0; c < 64; c++) {
    const float* p = sb + c * HW;
    float m = -1e30f;
#pragma unroll
    for (int t2 = 0; t2 < 9; t2++) {
      float v = okm[t2] ? p[lin[t2]] : -1e30f;
      m = fmaxf(m, v);
    }
    const float* wr = &wl[c * 32];
#pragma unroll
    for (int j = 0; j < 32; j++) acc[j] += m * wr[j];
  }
  if (act) {
    const float* xpre = frames + (size_t)fpre * 64 * HW + px;
    float* dp = dsum + (size_t)n * 64 * HW + px;
#pragma unroll
    for (int j = 0; j < 32; j++) {
      int o = o0 + j;
      float d3sum = dp[o * HW];
      for (int s = 1; s < nsplit; s++)
        d3sum += pext[(size_t)(s - 1) * PLANE + (size_t)n * 64 * HW + o * HW + px];
      float d = d3sum + (acc[j] + B3[o]) - 3.f * xpre[o * HW];
      dp[o * HW] = fabsf(d);
    }
  }
}

// ---------------------------------------------------------------------------
// Spatial mean of cat = [diff frames | t_out] per (nt, c).
// ---------------------------------------------------------------------------
__global__ void k_gmean(const float* __restrict__ dsum,
                        const float* __restrict__ t_out,
                        float* __restrict__ gmean)
{
  const int nt = blockIdx.x, c = blockIdx.y;
  const int b = nt >> 3, tt = nt & 7;
  const float* p = (tt < 7) ? (dsum + (size_t)((b * 7 + tt) * 64 + c) * HW)
                            : (t_out + (size_t)(b * 64 + c) * HW);
  const int tid = threadIdx.x;
  float s = 0.f;
  for (int i = tid; i < HW; i += 64) s += p[i];
#pragma unroll
  for (int o = 32; o > 0; o >>= 1) s += __shfl_down(s, o, 64);
  if (tid == 0) gmean[nt * 64 + c] = s * (1.f / HW);
}

// ---------------------------------------------------------------------------
// Gate: 1x1 conv 64->256 + sigmoid; store mult.
// ---------------------------------------------------------------------------
__global__ __launch_bounds__(256) void k_gate(
    const float* __restrict__ gmean, const float* __restrict__ gwT,
    const float* __restrict__ Bg, float* __restrict__ mult)
{
  __shared__ float gm[64];
  const int nt = blockIdx.x, co = threadIdx.x;
  if (co < 64) gm[co] = gmean[nt * 64 + co];
  __syncthreads();
  float a = 0.f;
#pragma unroll 8
  for (int c = 0; c < 64; c++) a += gm[c] * gwT[c * 256 + co];
  float pre = a + Bg[co];
  mult[nt * 256 + co] = 0.5f + 1.f / (1.f + expf(-pre));
}

// ---------------------------------------------------------------------------
// out = x * mult[nt,co]
// ---------------------------------------------------------------------------
__global__ void k_apply(const float* __restrict__ x,
                        const float* __restrict__ mult,
                        float* __restrict__ outp)
{
  const int i = blockIdx.x * 256 + threadIdx.x;
  const int plane = i / 196;
  const float m = mult[plane];
  float4 v = ((const float4*)x)[i];
  v.x *= m; v.y *= m; v.z *= m; v.w *= m;
  ((float4*)outp)[i] = v;
}

// ---------------------------------------------------------------------------
extern "C" void kernel_launch(void* const* d_in, const int* in_sizes, int n_in,
                              void* d_out, int out_size, void* d_ws, size_t ws_size,
                              hipStream_t stream)
{
  const float* x       = (const float*)d_in[0];
  const float* w_down  = (const float*)d_in[1];
  const float* b_down  = (const float*)d_in[2];
  const float* bn1_g   = (const float*)d_in[3];
  const float* bn1_b   = (const float*)d_in[4];
  const float* bn1_m   = (const float*)d_in[5];
  const float* bn1_v   = (const float*)d_in[6];
  const float* tconv_w = (const float*)d_in[7];
  const float* tconv_b = (const float*)d_in[8];
  const float* bnt_g   = (const float*)d_in[9];
  const float* bnt_b   = (const float*)d_in[10];
  const float* bnt_m   = (const float*)d_in[11];
  const float* bnt_v   = (const float*)d_in[12];
  const float* off3_w  = (const float*)d_in[13];
  const float* off3_b  = (const float*)d_in[14];
  const float* def3_w  = (const float*)d_in[15];
  const float* off5_w  = (const float*)d_in[16];
  const float* off5_b  = (const float*)d_in[17];
  const float* def5_w  = (const float*)d_in[18];
  const float* conv1_w = (const float*)d_in[19];
  const float* conv1_b = (const float*)d_in[20];
  const float* bn3_g   = (const float*)d_in[21];
  const float* bn3_b   = (const float*)d_in[22];
  const float* bn3_m   = (const float*)d_in[23];
  const float* bn3_v   = (const float*)d_in[24];
  const float* conv_w  = (const float*)d_in[25];
  const float* conv_b  = (const float*)d_in[26];
  const float* bn2_g   = (const float*)d_in[27];
  const float* bn2_b   = (const float*)d_in[28];
  const float* bn2_m   = (const float*)d_in[29];
  const float* bn2_v   = (const float*)d_in[30];

  float* ws = (float*)d_ws;
  float* out_b  = ws; ws += 64 * 64 * HW;
  float* U      = ws; ws += 8 * 192 * HW;
  float* t_out  = ws; ws += 8 * 64 * HW;
  float* off3b  = ws; ws += 56 * 18 * HW;
  float* off5b  = ws; ws += 56 * 50 * HW;
  float* dsum   = ws; ws += PLANE;
  float* gmean  = ws; ws += 64 * 64;
  float* multb  = ws; ws += 64 * 256;
  float* wdownT = ws; ws += 256 * 64;
  float* bias1  = ws; ws += 64;
  float* wtT    = ws; ws += 192 * 9 * 64;
  float* AtBt   = ws; ws += 128;
  float* def3T  = ws; ws += 9 * 64 * 64;
  float* def5T  = ws; ws += 25 * 64 * 64;
  float* c1T    = ws; ws += 64 * 64;
  float* B3     = ws; ws += 64;
  float* gwT    = ws; ws += 64 * 256;
  float* Bg     = ws; ws += 256;
  float* xT     = ws; ws += PLANE;                      // px-major f32
  __hip_bfloat16* wBs3 = (__hip_bfloat16*)ws; ws += 9216;    // 18432 bf16
  __hip_bfloat16* wBs5 = (__hip_bfloat16*)ws; ws += 51200;   // 102400 bf16
  __hip_bfloat16* xTbP = (__hip_bfloat16*)ws; ws += 56 * PADPX * 64 / 2;
  float* pext   = ws;                                   // extra partial planes

  // choose deform c-split factor from available workspace (constant per run)
  const size_t base = (size_t)(ws - (float*)d_ws);
  const size_t wsf = ws_size / sizeof(float);
  int CSPL = 1;
  if (wsf >= base + 3 * (size_t)PLANE) CSPL = 4;
  else if (wsf >= base + 1 * (size_t)PLANE) CSPL = 2;

  k_prep<<<256, 256, 0, stream>>>(
      w_down, b_down, bn1_g, bn1_b, bn1_m, bn1_v,
      tconv_w, tconv_b, bnt_g, bnt_b, bnt_m, bnt_v,
      off3_w, def3_w, off5_w, def5_w,
      conv1_w, conv1_b, bn3_g, bn3_b, bn3_m, bn3_v,
      conv_w, conv_b, bn2_g, bn2_b, bn2_m, bn2_v,
      wdownT, bias1, wtT, AtBt, wBs3, wBs5, def3T, def5T,
      c1T, B3, gwT, Bg);
  k_zerob<<<1792, 256, 0, stream>>>((float4*)xTbP);

  k_down<<<dim3(196, 2), 256, 0, stream>>>(x, wdownT, bias1, out_b);
  k_xpose<<<dim3(56, 13), 256, 0, stream>>>(out_b, xT, xTbP);
  k_makeU<<<1568, 256, 0, stream>>>(out_b, U);
  k_tconv<<<dim3(8, 4, 16), 256, 0, stream>>>(U, wtT, AtBt, t_out);
  // 686 blocks of 64 px each (43904 = 686*64 exact)
  k_offconv_mfma<3, 1, 18, 2, 9><<<686, 256, 0, stream>>>(xTbP, wBs3, off3_b, off3b);
  k_offconv_mfma<5, 2, 50, 4, 5><<<686, 256, 0, stream>>>(xTbP, wBs5, off5_b, off5b);
  k_deform<3, 1, false><<<dim3(PXBLK, CSPL), 256, 0, stream>>>(xT, off3b, def3T, dsum, pext);
  k_deform<5, 2, true><<<dim3(PXBLK, CSPL), 256, 0, stream>>>(xT, off5b, def5T, dsum, pext);
  k_davg_diff<<<dim3(PXBLK, 2), 256, 0, stream>>>(out_b, c1T, B3, dsum, pext, CSPL);
  k_gmean<<<dim3(64, 64), 64, 0, stream>>>(dsum, t_out, gmean);
  k_gate<<<64, 256, 0, stream>>>(gmean, gwT, Bg, multb);
  k_apply<<<12544, 256, 0, stream>>>(x, multb, (float*)d_out);
}